// Round 4
// baseline (378.379 us; speedup 1.0000x reference)
//
#include <hip/hip_runtime.h>

#define M_DIM 32
#define K_DIM 4096
#define N_DIM 16384
#define WR  32         // W rows per block (wave-shared; 2 x 16-col MFMA tiles)
#define NST 32         // stages per wave (K-split 4: each wave does 1024 = 32*32)
#define LP  40         // padded ushorts per LDS tile row (80 B: 16B-aligned, bank-spread)

using short8 = __attribute__((ext_vector_type(8))) short;
using f32x4  = __attribute__((ext_vector_type(4))) float;

__device__ __forceinline__ ushort f2bf_rne(float f) {
    unsigned u = __float_as_uint(f);
    u += 0x7fffu + ((u >> 16) & 1u);
    return (ushort)(u >> 16);
}

// Exact for integers |v| <= 256 (fits in 8 significand bits -> truncation lossless)
__device__ __forceinline__ ushort i2bf_exact(int v) {
    return (ushort)(__float_as_uint((float)v) >> 16);
}

__device__ __forceinline__ ushort4 cvt4(int4 v, int zero) {
    ushort4 o;
    o.x = i2bf_exact(v.x - zero);
    o.y = i2bf_exact(v.y - zero);
    o.z = i2bf_exact(v.z - zero);
    o.w = i2bf_exact(v.w - zero);
    return o;
}

__global__ __launch_bounds__(256) void prep_x_kernel(const float* __restrict__ x,
                                                     ushort* __restrict__ xb) {
    int i = blockIdx.x * blockDim.x + threadIdx.x;   // 32768 threads x 4 elems
    float4 v = reinterpret_cast<const float4*>(x)[i];
    ushort4 o;
    o.x = f2bf_rne(v.x); o.y = f2bf_rne(v.y); o.z = f2bf_rne(v.z); o.w = f2bf_rne(v.w);
    reinterpret_cast<ushort4*>(xb)[i] = o;
}

__global__ __launch_bounds__(256) void qgemm_kernel(
        const ushort* __restrict__ xb, const int* __restrict__ wq,
        const int* __restrict__ zerop, const float* __restrict__ scalep,
        const float* __restrict__ bias, float* __restrict__ out) {
    // Wave-private double-buffered stage tiles: no __syncthreads in the K-loop.
    __shared__ ushort wt[4][2][WR][LP];      // 20480 B
    __shared__ float  red[4][M_DIM][WR];     // 16384 B (split-K reduction)

    const int tid  = threadIdx.x;
    const int wave = tid >> 6;
    const int lane = tid & 63;
    const int quad = lane >> 4;
    const int l16  = lane & 15;
    const int n0   = blockIdx.x * WR;
    const int zero = *zerop;
    const int phase = blockIdx.x & (NST - 1);     // decorrelate k-phase across blocks
    const int kw   = wave << 10;                  // this wave's K-quarter

    // B staging: load j covers rows 8j..8j+7; 8 lanes per row -> 128 B contiguous runs.
    const int srow = lane >> 3;                   // 0..7
    const int scol = (lane & 7) << 2;             // int offset 0..28 in k-window
    const int* gB  = wq + (size_t)(n0 + srow) * K_DIM + kw + scol;

    // A-fragment: m = l16 (+16), k = kw + seff*32 + quad*8  (v1-verified layout)
    const ushort* axp0 = xb + (size_t)l16 * K_DIM + kw + (quad << 3);
    const ushort* axp1 = axp0 + 16 * K_DIM;

    f32x4 c00 = {0.f,0.f,0.f,0.f}, c01 = {0.f,0.f,0.f,0.f};
    f32x4 c10 = {0.f,0.f,0.f,0.f}, c11 = {0.f,0.f,0.f,0.f};

    // one-stage register prefetch
    int sn0 = (phase & (NST - 1)) << 5;
    int4 pb0 = *(const int4*)(gB +     sn0);
    int4 pb1 = *(const int4*)(gB + 32768 + sn0);
    int4 pb2 = *(const int4*)(gB + 65536 + sn0);
    int4 pb3 = *(const int4*)(gB + 98304 + sn0);
    short8 pa0 = *(const short8*)(axp0 + sn0);
    short8 pa1 = *(const short8*)(axp1 + sn0);

    #pragma unroll 2
    for (int s = 0; s < NST; ++s) {
        int4 b0i = pb0, b1i = pb1, b2i = pb2, b3i = pb3;
        short8 a0 = pa0, a1 = pa1;
        if (s + 1 < NST) {                         // issue next stage; stays in flight
            int sn = ((s + 1 + phase) & (NST - 1)) << 5;
            pb0 = *(const int4*)(gB +         sn);
            pb1 = *(const int4*)(gB + 32768 + sn);
            pb2 = *(const int4*)(gB + 65536 + sn);
            pb3 = *(const int4*)(gB + 98304 + sn);
            pa0 = *(const short8*)(axp0 + sn);
            pa1 = *(const short8*)(axp1 + sn);
        }

        // convert + wave-private LDS scatter (rows srow+8j), double-buffered
        ushort* wp = &wt[wave][s & 1][srow][scol];
        *(ushort4*)(wp)           = cvt4(b0i, zero);
        *(ushort4*)(wp +  8 * LP) = cvt4(b1i, zero);
        *(ushort4*)(wp + 16 * LP) = cvt4(b2i, zero);
        *(ushort4*)(wp + 24 * LP) = cvt4(b3i, zero);
        // Wave-internal RAW fence: LDS writes visible to this wave's reads.
        // lgkmcnt only — does NOT drain the global prefetch (vmcnt) above.
        asm volatile("s_waitcnt lgkmcnt(0)" ::: "memory");

        const ushort* rp = &wt[wave][s & 1][l16][quad << 3];
        short8 bf0 = *(const short8*)(rp);             // W rows n0+0..15
        short8 bf1 = *(const short8*)(rp + 16 * LP);   // W rows n0+16..31
        c00 = __builtin_amdgcn_mfma_f32_16x16x32_bf16(a0, bf0, c00, 0, 0, 0);
        c01 = __builtin_amdgcn_mfma_f32_16x16x32_bf16(a0, bf1, c01, 0, 0, 0);
        c10 = __builtin_amdgcn_mfma_f32_16x16x32_bf16(a1, bf0, c10, 0, 0, 0);
        c11 = __builtin_amdgcn_mfma_f32_16x16x32_bf16(a1, bf1, c11, 0, 0, 0);
    }

    // ---- split-K reduction (C layout v1-verified: row = quad*4+i, col = l16) ----
    #pragma unroll
    for (int i = 0; i < 4; ++i) {
        red[wave][(quad << 2) + i     ][l16     ] = c00[i];
        red[wave][(quad << 2) + i     ][l16 + 16] = c01[i];
        red[wave][(quad << 2) + i + 16][l16     ] = c10[i];
        red[wave][(quad << 2) + i + 16][l16 + 16] = c11[i];
    }
    __syncthreads();

    const float scale = *scalep;
    #pragma unroll
    for (int t = 0; t < 4; ++t) {
        int idx = tid + (t << 8);                  // 1024 outputs, 256 threads
        int row = idx >> 5;
        int col = idx & 31;
        float s = red[0][row][col] + red[1][row][col]
                + red[2][row][col] + red[3][row][col];
        out[(size_t)row * N_DIM + n0 + col] = fmaf(scale, s, bias[n0 + col]);
    }
}

extern "C" void kernel_launch(void* const* d_in, const int* in_sizes, int n_in,
                              void* d_out, int out_size, void* d_ws, size_t ws_size,
                              hipStream_t stream) {
    const float* x      = (const float*)d_in[0];
    const int*   wq     = (const int*)d_in[1];
    const int*   zerop  = (const int*)d_in[2];
    const float* scalep = (const float*)d_in[3];
    const float* bias   = (const float*)d_in[4];
    float*       out    = (float*)d_out;
    ushort*      xb     = (ushort*)d_ws;   // 32*4096 bf16 = 256 KB scratch

    prep_x_kernel<<<(M_DIM * K_DIM / 4) / 256, 256, 0, stream>>>(x, xb);
    qgemm_kernel<<<N_DIM / WR, 256, 0, stream>>>(xb, wq, zerop, scalep, bias, out);
}

// Round 5
// 361.280 us; speedup vs baseline: 1.0473x; 1.0473x over previous
//
#include <hip/hip_runtime.h>

#define M_DIM 32
#define K_DIM 4096
#define N_DIM 16384
#define BN 16          // weight rows per block
#define BK 128         // k (ints) per stage
#define NSTAGE 32      // K_DIM / BK
#define LROW 136       // ushorts per LDS row: 128 + 8 pad

using short8 = __attribute__((ext_vector_type(8))) short;
using f32x4  = __attribute__((ext_vector_type(4))) float;

// Workgroup barrier that waits only LDS ops (lgkmcnt) — does NOT drain the
// global-load (vmcnt) queue like __syncthreads does. Safe here: K-loop global
// loads are consumed only by the issuing wave (own vmcnt dependency).
#define LDS_BARRIER() asm volatile("s_waitcnt lgkmcnt(0)\n\ts_barrier" ::: "memory")

__device__ __forceinline__ ushort f2bf_rne(float f) {
    unsigned u = __float_as_uint(f);
    u += 0x7fffu + ((u >> 16) & 1u);
    return (ushort)(u >> 16);
}

// Exact for integers |v| <= 256 (fits in 8 significand bits -> truncation lossless)
__device__ __forceinline__ ushort i2bf_exact(int v) {
    return (ushort)(__float_as_uint((float)v) >> 16);
}

__device__ __forceinline__ ushort4 cvt4(int4 v, int zero) {
    ushort4 o;
    o.x = i2bf_exact(v.x - zero);
    o.y = i2bf_exact(v.y - zero);
    o.z = i2bf_exact(v.z - zero);
    o.w = i2bf_exact(v.w - zero);
    return o;
}

__global__ __launch_bounds__(256) void prep_x_kernel(const float* __restrict__ x,
                                                     ushort* __restrict__ xb) {
    int i = blockIdx.x * blockDim.x + threadIdx.x;   // 32768 threads x 4 elems
    float4 v = reinterpret_cast<const float4*>(x)[i];
    ushort4 o;
    o.x = f2bf_rne(v.x); o.y = f2bf_rne(v.y); o.z = f2bf_rne(v.z); o.w = f2bf_rne(v.w);
    reinterpret_cast<ushort4*>(xb)[i] = o;
}

__global__ __launch_bounds__(256) void qgemm_kernel(
        const ushort* __restrict__ xb, const int* __restrict__ wq,
        const int* __restrict__ zerop, const float* __restrict__ scalep,
        const float* __restrict__ bias, float* __restrict__ out) {
    __shared__ ushort tile[BN][LROW];        // 4352 B, single stage buffer
    __shared__ float  red[4][M_DIM][BN];     // 8 KB, split-K reduction

    const int tid  = threadIdx.x;
    const int wave = tid >> 6;
    const int lane = tid & 63;
    const int quad = lane >> 4;
    const int l16  = lane & 15;
    const int n0   = blockIdx.x * BN;
    const int zero = *zerop;
    const int phase = blockIdx.x & (NSTAGE - 1);   // decorrelate k-phase across blocks

    // Staging: each half-wave reads one row's 128 contiguous ints (512 B run).
    const int srow0 = wave * 4 + (lane >> 5);
    const int srow1 = srow0 + 2;
    const int sofs  = (lane & 31) * 4;             // int (and ushort) index in row
    const int* gb0 = wq + (size_t)(n0 + srow0) * K_DIM + sofs;
    const int* gb1 = wq + (size_t)(n0 + srow1) * K_DIM + sofs;

    // A-fragment base: m = l16 (+16 for tile 1), k = stage*128 + wave*32 + quad*8
    const int bofs = wave * 32 + quad * 8;
    const ushort* axp0 = xb + (size_t)l16 * K_DIM + bofs;
    const ushort* axp1 = axp0 + 16 * K_DIM;

    f32x4 acc0 = {0.f, 0.f, 0.f, 0.f};
    f32x4 acc1 = {0.f, 0.f, 0.f, 0.f};

    // ---- prologue: 2-stage B prefetch, 1-stage A prefetch ----
    const int k0p = phase * BK;
    const int k1p = ((1 + phase) & (NSTAGE - 1)) * BK;
    int4 c0 = *(const int4*)(gb0 + k0p);           // stage s   (written this iter)
    int4 c1 = *(const int4*)(gb1 + k0p);
    int4 d0 = *(const int4*)(gb0 + k1p);           // stage s+1 (in flight)
    int4 d1 = *(const int4*)(gb1 + k1p);
    short8 a0c = *(const short8*)(axp0 + k0p);     // A for stage s
    short8 a1c = *(const short8*)(axp1 + k0p);

    #pragma unroll 2
    for (int s = 0; s < NSTAGE; ++s) {
        int4 nb0, nb1;
        if (s + 2 < NSTAGE) {                      // B for stage s+2: 2 stages ahead
            int sn = ((s + 2 + phase) & (NSTAGE - 1)) * BK;
            nb0 = *(const int4*)(gb0 + sn);
            nb1 = *(const int4*)(gb1 + sn);
        }
        short8 na0, na1;
        if (s + 1 < NSTAGE) {                      // A for stage s+1 (L2-resident)
            int ka = ((s + 1 + phase) & (NSTAGE - 1)) * BK;
            na0 = *(const short8*)(axp0 + ka);
            na1 = *(const short8*)(axp1 + ka);
        }

        LDS_BARRIER();                             // WAR: all waves done reading tile
        *(ushort4*)&tile[srow0][sofs] = cvt4(c0, zero);
        *(ushort4*)&tile[srow1][sofs] = cvt4(c1, zero);
        LDS_BARRIER();                             // RAW: tile writes visible

        short8 bf = *(const short8*)&tile[l16][bofs];
        acc0 = __builtin_amdgcn_mfma_f32_16x16x32_bf16(a0c, bf, acc0, 0, 0, 0);
        acc1 = __builtin_amdgcn_mfma_f32_16x16x32_bf16(a1c, bf, acc1, 0, 0, 0);

        c0 = d0; c1 = d1;                          // rotate prefetch pipeline
        d0 = nb0; d1 = nb1;
        a0c = na0; a1c = na1;
    }

    // ---- split-K reduction (v1-verified layout: C row = quad*4+i, col = l16) ----
    __syncthreads();
    #pragma unroll
    for (int i = 0; i < 4; ++i) {
        red[wave][(quad << 2) + i][l16]      = acc0[i];
        red[wave][16 + (quad << 2) + i][l16] = acc1[i];
    }
    __syncthreads();

    const float scale = *scalep;
    #pragma unroll
    for (int t = 0; t < 2; ++t) {
        int idx = tid + (t << 8);                  // 512 outputs, 256 threads
        int row = idx >> 4;
        int c   = idx & 15;
        float s = red[0][row][c] + red[1][row][c] + red[2][row][c] + red[3][row][c];
        out[(size_t)row * N_DIM + n0 + c] = fmaf(scale, s, bias[n0 + c]);
    }
}

extern "C" void kernel_launch(void* const* d_in, const int* in_sizes, int n_in,
                              void* d_out, int out_size, void* d_ws, size_t ws_size,
                              hipStream_t stream) {
    const float* x      = (const float*)d_in[0];
    const int*   wq     = (const int*)d_in[1];
    const int*   zerop  = (const int*)d_in[2];
    const float* scalep = (const float*)d_in[3];
    const float* bias   = (const float*)d_in[4];
    float*       out    = (float*)d_out;
    ushort*      xb     = (ushort*)d_ws;   // 32*4096 bf16 = 256 KB scratch

    prep_x_kernel<<<(M_DIM * K_DIM / 4) / 256, 256, 0, stream>>>(x, xb);
    qgemm_kernel<<<N_DIM / BN, 256, 0, stream>>>(xb, wq, zerop, scalep, bias, out);
}